// Round 8
// baseline (185.028 us; speedup 1.0000x reference)
//
#include <hip/hip_runtime.h>
#include <hip/hip_bf16.h>

#define NN 100000
#define NE 600000
#define DD 128
#define SLOPE 0.22916666666666666f
#define NB1 98  // ceil(NN/1024)
#define SENT ((500u << 17) | 100000u)  // decodes to zero rows hb[NN], relb[500]
#define MAXSLOT 1000448               // >= NE + 4*NN
#define NTILE 6250                    // NN/16

typedef __attribute__((ext_vector_type(4))) float f32x4;
typedef __attribute__((ext_vector_type(4))) unsigned u32x4;
typedef __attribute__((ext_vector_type(8))) short s16x8;
typedef __attribute__((ext_vector_type(4))) short s16x4;

__device__ __forceinline__ unsigned short f2b(float f) {
  union { float f; unsigned u; } v; v.f = f;
  unsigned u = v.u;
  return (unsigned short)((u + 0x7fffu + ((u >> 16) & 1u)) >> 16);
}
__device__ __forceinline__ float b2f(short s) {
  union { unsigned u; float f; } v;
  v.u = ((unsigned)(unsigned short)s) << 16;
  return v.f;
}
// padded degree: 4*ceil(deg/4); deg recovered exactly from norm (deg0 -> 4 sentinel slots)
__device__ __forceinline__ int pdegf(float nm) {
  int d = (int)(1.0f / nm + 0.5f);
  return (d + 3) & ~3;
}

// fused: ent->bf16 (+zero row NN), rel->bf16 (+zero row 500), Wt build in
// MFMA-FRAGMENT ORDER: Wt[L][(n*8+k)*64+lane][0..7] = W[c=n*16+(lane&15)]
// [kk=k*32+(lane>>4)*8+t] -> mm LDS staging linear, ds_reads conflict-free.
__global__ void prep_all(const float* __restrict__ ent, const float* __restrict__ rel,
                         const float* __restrict__ Wr0, const float* __restrict__ Wl0,
                         const float* __restrict__ Wr1, const float* __restrict__ Wl1,
                         unsigned short* __restrict__ entb, unsigned short* __restrict__ relb,
                         unsigned short* __restrict__ Wt) {
  int i = blockIdx.x * blockDim.x + threadIdx.x;
  if (i < (NN + 1) * 16) {
    s16x8 o = {0, 0, 0, 0, 0, 0, 0, 0};
    if (i < NN * 16) {
      f32x4 v0 = *(const f32x4*)(ent + (size_t)i * 8);
      f32x4 v1 = *(const f32x4*)(ent + (size_t)i * 8 + 4);
      o[0] = (short)f2b(v0[0]); o[1] = (short)f2b(v0[1]);
      o[2] = (short)f2b(v0[2]); o[3] = (short)f2b(v0[3]);
      o[4] = (short)f2b(v1[0]); o[5] = (short)f2b(v1[1]);
      o[6] = (short)f2b(v1[2]); o[7] = (short)f2b(v1[3]);
    }
    *(s16x8*)(entb + (size_t)i * 8) = o;
  }
  if (i < 501 * 16) {
    s16x8 o = {0, 0, 0, 0, 0, 0, 0, 0};
    if (i < 500 * 16) {
      f32x4 v0 = *(const f32x4*)(rel + (size_t)i * 8);
      f32x4 v1 = *(const f32x4*)(rel + (size_t)i * 8 + 4);
      o[0] = (short)f2b(v0[0]); o[1] = (short)f2b(v0[1]);
      o[2] = (short)f2b(v0[2]); o[3] = (short)f2b(v0[3]);
      o[4] = (short)f2b(v1[0]); o[5] = (short)f2b(v1[1]);
      o[6] = (short)f2b(v1[2]); o[7] = (short)f2b(v1[3]);
    }
    *(s16x8*)(relb + (size_t)i * 8) = o;
  }
  if (i < 8192) {  // 2 layers x 4096 fragment units x 8 shorts
    int L = i >> 12, rem = i & 4095;
    int n = rem >> 9, k = (rem >> 6) & 7, lane = rem & 63;
    int c = n * 16 + (lane & 15);
    int kk0 = k * 32 + (lane >> 4) * 8;
    const float* Wr = L ? Wr1 : Wr0;
    const float* Wl = L ? Wl1 : Wl0;
    s16x8 o;
#pragma unroll
    for (int t = 0; t < 8; t++) {
      int kk = kk0 + t;
      float v = (kk < DD) ? Wr[kk * DD + c] : Wl[(kk - DD) * DD + c];
      o[t] = (short)f2b(v);
    }
    *(s16x8*)(Wt + (size_t)i * 8) = o;
  }
}

// ---------- CSR build: scan padded degrees, linked-list, compact ----------
__global__ void scan_a(const float* __restrict__ norm, int* __restrict__ psum) {
  __shared__ int lds[256];
  int b = blockIdx.x, t = threadIdx.x;
  int base = b * 1024 + t * 4;
  int s = 0;
#pragma unroll
  for (int j = 0; j < 4; j++) { int i = base + j; if (i < NN) s += pdegf(norm[i]); }
  lds[t] = s; __syncthreads();
  for (int st = 128; st > 0; st >>= 1) { if (t < st) lds[t] += lds[t + st]; __syncthreads(); }
  if (t == 0) psum[b] = lds[0];
}

__global__ void scan_b(int* __restrict__ psum, int* __restrict__ off) {
  __shared__ int lds[128];
  int t = threadIdx.x;
  lds[t] = (t < NB1) ? psum[t] : 0; __syncthreads();
  for (int st = 1; st < 128; st <<= 1) {
    int v = (t >= st) ? lds[t - st] : 0;
    __syncthreads();
    lds[t] += v;
    __syncthreads();
  }
  if (t == 127) off[NN] = lds[127];  // total padded slots
  if (t < NB1) psum[t] = t ? lds[t - 1] : 0;
}

__global__ void scan_c(const float* __restrict__ norm, const int* __restrict__ psum,
                       int* __restrict__ off) {
  __shared__ int lds[256];
  int b = blockIdx.x, t = threadIdx.x;
  int base = b * 1024 + t * 4;
  int v[4]; int s = 0;
#pragma unroll
  for (int j = 0; j < 4; j++) { int i = base + j; v[j] = (i < NN) ? pdegf(norm[i]) : 0; s += v[j]; }
  lds[t] = s; __syncthreads();
  for (int st = 1; st < 256; st <<= 1) {
    int u = (t >= st) ? lds[t - st] : 0;
    __syncthreads();
    lds[t] += u;
    __syncthreads();
  }
  int run = (t ? lds[t - 1] : 0) + psum[b];
#pragma unroll
  for (int j = 0; j < 4; j++) {
    int i = base + j;
    if (i < NN) { off[i] = run; run += v[j]; }
  }
}

// per-edge: push e onto dst's list. nxt written coalesced; atomics hit L2-resident head.
__global__ void link_build(const int* __restrict__ dst, int* __restrict__ head,
                           int* __restrict__ nxt) {
  int i = blockIdx.x * blockDim.x + threadIdx.x;
  int e0 = i * 2;
  if (e0 + 1 < NE) {
    int d0 = dst[e0], d1 = dst[e0 + 1];
    nxt[e0] = atomicExch(&head[d0], e0);
    nxt[e0 + 1] = atomicExch(&head[d1], e0 + 1);
  } else if (e0 < NE) {
    nxt[e0] = atomicExch(&head[dst[e0]], e0);
  }
}

// per-node: walk chain, write packed (src|rid<<17) slots sequentially, sentinel-pad to off[g+1].
__global__ void compact(const int* __restrict__ head, const int* __restrict__ nxt,
                        const int* __restrict__ src, const int* __restrict__ rid,
                        const int* __restrict__ off, unsigned* __restrict__ epack) {
  int g = blockIdx.x * blockDim.x + threadIdx.x;
  if (g >= NN) return;
  int slot = off[g], endp = off[g + 1];
  int e = head[g];
  while (e >= 0) {
    epack[slot++] = (unsigned)src[e] | ((unsigned)rid[e] << 17);
    e = nxt[e];
  }
  while (slot < endp) epack[slot++] = SENT;
}

// layer-1 gather: h + rel; emits preb = bf16(nm*(Sh+Sr)) and relaggn = bf16(nm*Sr)
__global__ void gather1(const unsigned short* __restrict__ hb, const unsigned short* __restrict__ relb,
                        const float* __restrict__ norm, const int* __restrict__ off,
                        const unsigned* __restrict__ epack,
                        unsigned short* __restrict__ preb, unsigned short* __restrict__ relaggn) {
  int gid = blockIdx.x * blockDim.x + threadIdx.x;
  int g = gid >> 5;
  if (g >= NN) return;
  int c = (gid & 31) << 2;
  int beg = off[g], end = off[g + 1];
  float h0 = 0.f, h1 = 0.f, h2 = 0.f, h3 = 0.f;
  float r0 = 0.f, r1 = 0.f, r2 = 0.f, r3 = 0.f;
  for (int e = beg; e < end; e += 4) {
    u32x4 w = *(const u32x4*)(epack + e);
    s16x4 hv[4], rv[4];
#pragma unroll
    for (int j = 0; j < 4; j++) {
      int s = (int)(w[j] & 0x1FFFFu);
      int r = (int)(w[j] >> 17);
      hv[j] = *(const s16x4*)(hb + (size_t)s * DD + c);
      rv[j] = *(const s16x4*)(relb + (size_t)r * DD + c);
    }
#pragma unroll
    for (int j = 0; j < 4; j++) {
      h0 += b2f(hv[j][0]); h1 += b2f(hv[j][1]);
      h2 += b2f(hv[j][2]); h3 += b2f(hv[j][3]);
      r0 += b2f(rv[j][0]); r1 += b2f(rv[j][1]);
      r2 += b2f(rv[j][2]); r3 += b2f(rv[j][3]);
    }
  }
  float nm = norm[g];
  s16x4 p, q;
  p[0] = (short)f2b((h0 + r0) * nm); p[1] = (short)f2b((h1 + r1) * nm);
  p[2] = (short)f2b((h2 + r2) * nm); p[3] = (short)f2b((h3 + r3) * nm);
  q[0] = (short)f2b(r0 * nm); q[1] = (short)f2b(r1 * nm);
  q[2] = (short)f2b(r2 * nm); q[3] = (short)f2b(r3 * nm);
  *(s16x4*)(preb + (size_t)g * DD + c) = p;
  *(s16x4*)(relaggn + (size_t)g * DD + c) = q;
}

// layer-2 gather: h only, init from relaggn
__global__ void gather2(const unsigned short* __restrict__ hb, const unsigned short* __restrict__ relaggn,
                        const float* __restrict__ norm, const int* __restrict__ off,
                        const unsigned* __restrict__ epack, unsigned short* __restrict__ preb) {
  int gid = blockIdx.x * blockDim.x + threadIdx.x;
  int g = gid >> 5;
  if (g >= NN) return;
  int c = (gid & 31) << 2;
  int beg = off[g], end = off[g + 1];
  float h0 = 0.f, h1 = 0.f, h2 = 0.f, h3 = 0.f;
  for (int e = beg; e < end; e += 4) {
    u32x4 w = *(const u32x4*)(epack + e);
    s16x4 hv[4];
#pragma unroll
    for (int j = 0; j < 4; j++) {
      int s = (int)(w[j] & 0x1FFFFu);
      hv[j] = *(const s16x4*)(hb + (size_t)s * DD + c);
    }
#pragma unroll
    for (int j = 0; j < 4; j++) {
      h0 += b2f(hv[j][0]); h1 += b2f(hv[j][1]);
      h2 += b2f(hv[j][2]); h3 += b2f(hv[j][3]);
    }
  }
  float nm = norm[g];
  s16x4 ra = *(const s16x4*)(relaggn + (size_t)g * DD + c);
  s16x4 p;
  p[0] = (short)f2b(__builtin_fmaf(h0, nm, b2f(ra[0])));
  p[1] = (short)f2b(__builtin_fmaf(h1, nm, b2f(ra[1])));
  p[2] = (short)f2b(__builtin_fmaf(h2, nm, b2f(ra[2])));
  p[3] = (short)f2b(__builtin_fmaf(h3, nm, b2f(ra[3])));
  *(s16x4*)(preb + (size_t)g * DD + c) = p;
}

// out = leaky_relu([preb ; hb] @ Wt). A-frags direct from global (bf16),
// fragment-major B in LDS (64KB, linear stage, conflict-free reads).
// Grid 512 = 2 blocks/CU; each wave owns tiles gw and gw+4096.
template <int OUTF32>
__launch_bounds__(512, 4)
__global__ void layer_mm(const unsigned short* __restrict__ preb, const unsigned short* __restrict__ hb,
                         const unsigned short* __restrict__ Wt, void* __restrict__ outp) {
  __shared__ unsigned short Blds[32768];
  int tid = threadIdx.x;
  int wave = tid >> 6, lane = tid & 63;
  int l16 = lane & 15, lhi = lane >> 4;

  for (int i = tid; i < 4096; i += 512)
    *(s16x8*)(&Blds[(size_t)i * 8]) = *(const s16x8*)(Wt + (size_t)i * 8);
  __syncthreads();

  const unsigned short* Bl = &Blds[lane * 8];

  int gw = blockIdx.x * 8 + wave;  // 0..4095
  int t0 = gw, t1 = gw + 4096;
  bool has1 = t1 < NTILE;

  const unsigned short* Ap0 = preb + (size_t)(t0 * 16 + l16) * DD + lhi * 8;
  const unsigned short* Ah0 = hb + (size_t)(t0 * 16 + l16) * DD + lhi * 8;
  s16x8 a0[8], a1[8];
#pragma unroll
  for (int ks = 0; ks < 4; ks++) a0[ks] = *(const s16x8*)(Ap0 + ks * 32);
#pragma unroll
  for (int ks = 0; ks < 4; ks++) a0[4 + ks] = *(const s16x8*)(Ah0 + ks * 32);
  if (has1) {
    const unsigned short* Ap1 = preb + (size_t)(t1 * 16 + l16) * DD + lhi * 8;
    const unsigned short* Ah1 = hb + (size_t)(t1 * 16 + l16) * DD + lhi * 8;
#pragma unroll
    for (int ks = 0; ks < 4; ks++) a1[ks] = *(const s16x8*)(Ap1 + ks * 32);
#pragma unroll
    for (int ks = 0; ks < 4; ks++) a1[4 + ks] = *(const s16x8*)(Ah1 + ks * 32);
  }

  {
    f32x4 acc[8];
#pragma unroll
    for (int n = 0; n < 8; n++) acc[n] = (f32x4){0.f, 0.f, 0.f, 0.f};
#pragma unroll
    for (int n = 0; n < 8; n++) {
#pragma unroll
      for (int k = 0; k < 8; k++) {
        s16x8 b = *(const s16x8*)(Bl + (n * 8 + k) * 512);
        acc[n] = __builtin_amdgcn_mfma_f32_16x16x32_bf16(a0[k], b, acc[n], 0, 0, 0);
      }
    }
    int r0 = t0 * 16;
#pragma unroll
    for (int n = 0; n < 8; n++) {
#pragma unroll
      for (int j = 0; j < 4; j++) {
        int gr = r0 + lhi * 4 + j;
        float x = acc[n][j];
        x = x > 0.f ? x : x * SLOPE;
        if (OUTF32) ((float*)outp)[(size_t)gr * DD + n * 16 + l16] = x;
        else ((unsigned short*)outp)[(size_t)gr * DD + n * 16 + l16] = f2b(x);
      }
    }
  }
  if (has1) {
    f32x4 acc[8];
#pragma unroll
    for (int n = 0; n < 8; n++) acc[n] = (f32x4){0.f, 0.f, 0.f, 0.f};
#pragma unroll
    for (int n = 0; n < 8; n++) {
#pragma unroll
      for (int k = 0; k < 8; k++) {
        s16x8 b = *(const s16x8*)(Bl + (n * 8 + k) * 512);
        acc[n] = __builtin_amdgcn_mfma_f32_16x16x32_bf16(a1[k], b, acc[n], 0, 0, 0);
      }
    }
    int r0 = t1 * 16;
#pragma unroll
    for (int n = 0; n < 8; n++) {
#pragma unroll
      for (int j = 0; j < 4; j++) {
        int gr = r0 + lhi * 4 + j;
        float x = acc[n][j];
        x = x > 0.f ? x : x * SLOPE;
        if (OUTF32) ((float*)outp)[(size_t)gr * DD + n * 16 + l16] = x;
        else ((unsigned short*)outp)[(size_t)gr * DD + n * 16 + l16] = f2b(x);
      }
    }
  }
}

extern "C" void kernel_launch(void* const* d_in, const int* in_sizes, int n_in,
                              void* d_out, int out_size, void* d_ws, size_t ws_size,
                              hipStream_t stream) {
  const float* ent  = (const float*)d_in[0];
  const float* rel  = (const float*)d_in[1];
  const float* norm = (const float*)d_in[2];
  const float* Wr0  = (const float*)d_in[3];
  const float* Wl0  = (const float*)d_in[4];
  const float* Wr1  = (const float*)d_in[5];
  const float* Wl1  = (const float*)d_in[6];
  const int* src = (const int*)d_in[7];
  const int* dst = (const int*)d_in[8];
  const int* rid = (const int*)d_in[9];
  float* out = (float*)d_out;

  char* ws = (char*)d_ws;
  unsigned short* entb    = (unsigned short*)ws;                  // (NN+1)*256 = 25,600,256 B
  unsigned short* preb    = (unsigned short*)(ws + 25600256);     // 25,600,000 B
  unsigned short* relaggn = (unsigned short*)(ws + 51200256);     // 25,600,000 B
  unsigned short* Wt      = (unsigned short*)(ws + 76800256);     //    131,072 B (fragment-major)
  unsigned short* relb    = (unsigned short*)(ws + 76931328);     // 501*256 = 128,256 B
  int* off   = (int*)(ws + 77059584);                             //    400,016 B
  int* head  = (int*)(ws + 77459600);                             //    400,000 B
  int* psum  = (int*)(ws + 77859600);                             //        512 B
  unsigned* epack = (unsigned*)(ws + 77860112);                   //  4,001,792 B
  int* nxt   = (int*)relaggn;  // alias: relaggn dead until gather1; nxt dead after compact

  prep_all<<<((NN + 1) * 16 + 255) / 256, 256, 0, stream>>>(ent, rel, Wr0, Wl0, Wr1, Wl1, entb, relb, Wt);

  hipMemsetAsync(head, 0xFF, (size_t)NN * 4, stream);  // head = -1
  link_build<<<(NE / 2 + 255) / 256, 256, 0, stream>>>(dst, head, nxt);
  scan_a<<<NB1, 256, 0, stream>>>(norm, psum);
  scan_b<<<1, 128, 0, stream>>>(psum, off);
  scan_c<<<NB1, 256, 0, stream>>>(norm, psum, off);
  compact<<<(NN + 255) / 256, 256, 0, stream>>>(head, nxt, src, rid, off, epack);

  const int gb = (NN * 32 + 255) / 256;

  // layer 1: gather h+rel from entb/relb; mm writes bf16 h1 in place of entb
  gather1<<<gb, 256, 0, stream>>>(entb, relb, norm, off, epack, preb, relaggn);
  layer_mm<0><<<512, 512, 0, stream>>>(preb, entb, Wt, entb);

  // layer 2: gather h only (rel part cached in relaggn); mm writes fp32 d_out
  gather2<<<gb, 256, 0, stream>>>(entb, relaggn, norm, off, epack, preb);
  layer_mm<1><<<512, 512, 0, stream>>>(preb, entb, Wt + 32768, out);
}

// Round 9
// 160.848 us; speedup vs baseline: 1.1503x; 1.1503x over previous
//
#include <hip/hip_runtime.h>
#include <hip/hip_bf16.h>

#define NN 100000
#define NE 600000
#define DD 128
#define SLOPE 0.22916666666666666f
#define NB1 98  // ceil(NN/1024)
#define SENT ((500u << 17) | 100000u)  // decodes to zero rows hb[NN], relb[500]
#define NTILE 6250                    // NN/16
#define NBKT 196                      // ceil(NN/512)
#define EPB 2048                      // edges per bin_scatter block
#define CAP 12288                     // staging capacity per bucket (avg ~3072)

typedef __attribute__((ext_vector_type(4))) float f32x4;
typedef __attribute__((ext_vector_type(4))) unsigned u32x4;
typedef __attribute__((ext_vector_type(8))) short s16x8;
typedef __attribute__((ext_vector_type(4))) short s16x4;

__device__ __forceinline__ unsigned short f2b(float f) {
  union { float f; unsigned u; } v; v.f = f;
  unsigned u = v.u;
  return (unsigned short)((u + 0x7fffu + ((u >> 16) & 1u)) >> 16);
}
__device__ __forceinline__ float b2f(short s) {
  union { unsigned u; float f; } v;
  v.u = ((unsigned)(unsigned short)s) << 16;
  return v.f;
}
// padded degree: 4*ceil(deg/4); deg from norm (deg0 nodes -> 4 sentinel slots)
__device__ __forceinline__ int pdegf(float nm) {
  int d = (int)(1.0f / nm + 0.5f);
  return (d + 3) & ~3;
}

// fused: ent->bf16 (+zero row NN), rel->bf16 (+zero row 500), Wt build in
// MFMA-FRAGMENT ORDER: Wt[L][(n*8+k)*64+lane][0..7] = W[c=n*16+(lane&15)]
// [kk=k*32+(lane>>4)*8+t] -> mm LDS staging linear, ds_reads conflict-free.
__global__ void prep_all(const float* __restrict__ ent, const float* __restrict__ rel,
                         const float* __restrict__ Wr0, const float* __restrict__ Wl0,
                         const float* __restrict__ Wr1, const float* __restrict__ Wl1,
                         unsigned short* __restrict__ entb, unsigned short* __restrict__ relb,
                         unsigned short* __restrict__ Wt) {
  int i = blockIdx.x * blockDim.x + threadIdx.x;
  if (i < (NN + 1) * 16) {
    s16x8 o = {0, 0, 0, 0, 0, 0, 0, 0};
    if (i < NN * 16) {
      f32x4 v0 = *(const f32x4*)(ent + (size_t)i * 8);
      f32x4 v1 = *(const f32x4*)(ent + (size_t)i * 8 + 4);
      o[0] = (short)f2b(v0[0]); o[1] = (short)f2b(v0[1]);
      o[2] = (short)f2b(v0[2]); o[3] = (short)f2b(v0[3]);
      o[4] = (short)f2b(v1[0]); o[5] = (short)f2b(v1[1]);
      o[6] = (short)f2b(v1[2]); o[7] = (short)f2b(v1[3]);
    }
    *(s16x8*)(entb + (size_t)i * 8) = o;
  }
  if (i < 501 * 16) {
    s16x8 o = {0, 0, 0, 0, 0, 0, 0, 0};
    if (i < 500 * 16) {
      f32x4 v0 = *(const f32x4*)(rel + (size_t)i * 8);
      f32x4 v1 = *(const f32x4*)(rel + (size_t)i * 8 + 4);
      o[0] = (short)f2b(v0[0]); o[1] = (short)f2b(v0[1]);
      o[2] = (short)f2b(v0[2]); o[3] = (short)f2b(v0[3]);
      o[4] = (short)f2b(v1[0]); o[5] = (short)f2b(v1[1]);
      o[6] = (short)f2b(v1[2]); o[7] = (short)f2b(v1[3]);
    }
    *(s16x8*)(relb + (size_t)i * 8) = o;
  }
  if (i < 8192) {  // 2 layers x 4096 fragment units x 8 shorts
    int L = i >> 12, rem = i & 4095;
    int n = rem >> 9, k = (rem >> 6) & 7, lane = rem & 63;
    int c = n * 16 + (lane & 15);
    int kk0 = k * 32 + (lane >> 4) * 8;
    const float* Wr = L ? Wr1 : Wr0;
    const float* Wl = L ? Wl1 : Wl0;
    s16x8 o;
#pragma unroll
    for (int t = 0; t < 8; t++) {
      int kk = kk0 + t;
      float v = (kk < DD) ? Wr[kk * DD + c] : Wl[(kk - DD) * DD + c];
      o[t] = (short)f2b(v);
    }
    *(s16x8*)(Wt + (size_t)i * 8) = o;
  }
}

// ---------- CSR build: scan padded degrees, XCD-local binned scatter ----------
__global__ void scan_a(const float* __restrict__ norm, int* __restrict__ psum) {
  __shared__ int lds[256];
  int b = blockIdx.x, t = threadIdx.x;
  int base = b * 1024 + t * 4;
  int s = 0;
#pragma unroll
  for (int j = 0; j < 4; j++) { int i = base + j; if (i < NN) s += pdegf(norm[i]); }
  lds[t] = s; __syncthreads();
  for (int st = 128; st > 0; st >>= 1) { if (t < st) lds[t] += lds[t + st]; __syncthreads(); }
  if (t == 0) psum[b] = lds[0];
}

__global__ void scan_b(int* __restrict__ psum, int* __restrict__ off) {
  __shared__ int lds[128];
  int t = threadIdx.x;
  lds[t] = (t < NB1) ? psum[t] : 0; __syncthreads();
  for (int st = 1; st < 128; st <<= 1) {
    int v = (t >= st) ? lds[t - st] : 0;
    __syncthreads();
    lds[t] += v;
    __syncthreads();
  }
  if (t == 127) off[NN] = lds[127];  // total padded slots
  if (t < NB1) psum[t] = t ? lds[t - 1] : 0;
}

__global__ void scan_c(const float* __restrict__ norm, const int* __restrict__ psum,
                       int* __restrict__ off) {
  __shared__ int lds[256];
  int b = blockIdx.x, t = threadIdx.x;
  int base = b * 1024 + t * 4;
  int v[4]; int s = 0;
#pragma unroll
  for (int j = 0; j < 4; j++) { int i = base + j; v[j] = (i < NN) ? pdegf(norm[i]) : 0; s += v[j]; }
  lds[t] = s; __syncthreads();
  for (int st = 1; st < 256; st <<= 1) {
    int u = (t >= st) ? lds[t - st] : 0;
    __syncthreads();
    lds[t] += u;
    __syncthreads();
  }
  int run = (t ? lds[t - 1] : 0) + psum[b];
#pragma unroll
  for (int j = 0; j < 4; j++) {
    int i = base + j;
    if (i < NN) { off[i] = run; run += v[j]; }
  }
}

// phase 1: per-block LDS histogram over 196 buckets (dst>>9), one global
// atomicAdd per (block,bucket) to reserve a staging range, then rank+write.
// Each block's writes per bucket are sequential -> lines filled before eviction.
__global__ void bin_scatter(const int* __restrict__ src, const int* __restrict__ dst,
                            const int* __restrict__ rid, int* __restrict__ bktcur,
                            unsigned* __restrict__ sval, unsigned short* __restrict__ sdst) {
  __shared__ int hist[NBKT];
  __shared__ int base[NBKT];
  __shared__ int rnk[NBKT];
  int tid = threadIdx.x;
  int e0 = blockIdx.x * EPB;
  for (int t = tid; t < NBKT; t += 256) hist[t] = 0;
  __syncthreads();
  int d[8];
#pragma unroll
  for (int j = 0; j < 8; j++) {
    int idx = tid + j * 256;
    int e = e0 + idx;
    d[j] = (e < NE) ? dst[e] : -1;
    if (d[j] >= 0) atomicAdd(&hist[d[j] >> 9], 1);
  }
  __syncthreads();
  for (int t = tid; t < NBKT; t += 256) {
    base[t] = hist[t] ? atomicAdd(&bktcur[t], hist[t]) : 0;
    rnk[t] = 0;
  }
  __syncthreads();
#pragma unroll
  for (int j = 0; j < 8; j++) {
    if (d[j] >= 0) {
      int e = e0 + tid + j * 256;
      int b = d[j] >> 9;
      int r = atomicAdd(&rnk[b], 1);
      int pos = base[b] + r;
      if (pos < CAP) {
        sval[(size_t)b * CAP + pos] = (unsigned)src[e] | ((unsigned)rid[e] << 17);
        sdst[(size_t)b * CAP + pos] = (unsigned short)(d[j] & 511);
      }
    }
  }
}

// phase 2: one block per bucket; LDS cursors seeded from off[]; place staged
// edges at final epack slots (writes stay inside the bucket's contiguous
// window), then sentinel-pad each node from its placed count to off[g+1].
__global__ void bin_sort(const int* __restrict__ bktcur, const unsigned* __restrict__ sval,
                         const unsigned short* __restrict__ sdst, const int* __restrict__ off,
                         unsigned* __restrict__ epack) {
  __shared__ int cur[512];
  int b = blockIdx.x, tid = threadIdx.x;
  int g0 = b << 9;
  for (int t = tid; t < 512; t += 256) {
    int g = g0 + t;
    cur[t] = (g < NN) ? off[g] : 0;
  }
  __syncthreads();
  int scnt = min(bktcur[b], CAP);
  for (int i = tid; i < scnt; i += 256) {
    unsigned v = sval[(size_t)b * CAP + i];
    int gl = sdst[(size_t)b * CAP + i];
    int pos = atomicAdd(&cur[gl], 1);
    epack[pos] = v;
  }
  __syncthreads();
  for (int t = tid; t < 512; t += 256) {
    int g = g0 + t;
    if (g < NN) {
      int s = cur[t], e = off[g + 1];
      for (; s < e; s++) epack[s] = SENT;
    }
  }
}

// layer-1 gather: h + rel; emits preb = bf16(nm*(Sh+Sr)) and relaggn = bf16(nm*Sr)
__global__ void gather1(const unsigned short* __restrict__ hb, const unsigned short* __restrict__ relb,
                        const float* __restrict__ norm, const int* __restrict__ off,
                        const unsigned* __restrict__ epack,
                        unsigned short* __restrict__ preb, unsigned short* __restrict__ relaggn) {
  int gid = blockIdx.x * blockDim.x + threadIdx.x;
  int g = gid >> 5;
  if (g >= NN) return;
  int c = (gid & 31) << 2;
  int beg = off[g], end = off[g + 1];
  float h0 = 0.f, h1 = 0.f, h2 = 0.f, h3 = 0.f;
  float r0 = 0.f, r1 = 0.f, r2 = 0.f, r3 = 0.f;
  for (int e = beg; e < end; e += 4) {
    u32x4 w = *(const u32x4*)(epack + e);
    s16x4 hv[4], rv[4];
#pragma unroll
    for (int j = 0; j < 4; j++) {
      int s = (int)(w[j] & 0x1FFFFu);
      int r = (int)(w[j] >> 17);
      hv[j] = *(const s16x4*)(hb + (size_t)s * DD + c);
      rv[j] = *(const s16x4*)(relb + (size_t)r * DD + c);
    }
#pragma unroll
    for (int j = 0; j < 4; j++) {
      h0 += b2f(hv[j][0]); h1 += b2f(hv[j][1]);
      h2 += b2f(hv[j][2]); h3 += b2f(hv[j][3]);
      r0 += b2f(rv[j][0]); r1 += b2f(rv[j][1]);
      r2 += b2f(rv[j][2]); r3 += b2f(rv[j][3]);
    }
  }
  float nm = norm[g];
  s16x4 p, q;
  p[0] = (short)f2b((h0 + r0) * nm); p[1] = (short)f2b((h1 + r1) * nm);
  p[2] = (short)f2b((h2 + r2) * nm); p[3] = (short)f2b((h3 + r3) * nm);
  q[0] = (short)f2b(r0 * nm); q[1] = (short)f2b(r1 * nm);
  q[2] = (short)f2b(r2 * nm); q[3] = (short)f2b(r3 * nm);
  *(s16x4*)(preb + (size_t)g * DD + c) = p;
  *(s16x4*)(relaggn + (size_t)g * DD + c) = q;
}

// layer-2 gather: h only, init from relaggn
__global__ void gather2(const unsigned short* __restrict__ hb, const unsigned short* __restrict__ relaggn,
                        const float* __restrict__ norm, const int* __restrict__ off,
                        const unsigned* __restrict__ epack, unsigned short* __restrict__ preb) {
  int gid = blockIdx.x * blockDim.x + threadIdx.x;
  int g = gid >> 5;
  if (g >= NN) return;
  int c = (gid & 31) << 2;
  int beg = off[g], end = off[g + 1];
  float h0 = 0.f, h1 = 0.f, h2 = 0.f, h3 = 0.f;
  for (int e = beg; e < end; e += 4) {
    u32x4 w = *(const u32x4*)(epack + e);
    s16x4 hv[4];
#pragma unroll
    for (int j = 0; j < 4; j++) {
      int s = (int)(w[j] & 0x1FFFFu);
      hv[j] = *(const s16x4*)(hb + (size_t)s * DD + c);
    }
#pragma unroll
    for (int j = 0; j < 4; j++) {
      h0 += b2f(hv[j][0]); h1 += b2f(hv[j][1]);
      h2 += b2f(hv[j][2]); h3 += b2f(hv[j][3]);
    }
  }
  float nm = norm[g];
  s16x4 ra = *(const s16x4*)(relaggn + (size_t)g * DD + c);
  s16x4 p;
  p[0] = (short)f2b(__builtin_fmaf(h0, nm, b2f(ra[0])));
  p[1] = (short)f2b(__builtin_fmaf(h1, nm, b2f(ra[1])));
  p[2] = (short)f2b(__builtin_fmaf(h2, nm, b2f(ra[2])));
  p[3] = (short)f2b(__builtin_fmaf(h3, nm, b2f(ra[3])));
  *(s16x4*)(preb + (size_t)g * DD + c) = p;
}

// out = leaky_relu([preb ; hb] @ Wt). A-frags direct from global (bf16),
// fragment-major B in LDS (64KB, linear stage, conflict-free reads).
// Grid 512 = 2 blocks/CU; each wave owns tiles gw and gw+4096.
template <int OUTF32>
__launch_bounds__(512, 4)
__global__ void layer_mm(const unsigned short* __restrict__ preb, const unsigned short* __restrict__ hb,
                         const unsigned short* __restrict__ Wt, void* __restrict__ outp) {
  __shared__ unsigned short Blds[32768];
  int tid = threadIdx.x;
  int wave = tid >> 6, lane = tid & 63;
  int l16 = lane & 15, lhi = lane >> 4;

  for (int i = tid; i < 4096; i += 512)
    *(s16x8*)(&Blds[(size_t)i * 8]) = *(const s16x8*)(Wt + (size_t)i * 8);
  __syncthreads();

  const unsigned short* Bl = &Blds[lane * 8];

  int gw = blockIdx.x * 8 + wave;  // 0..4095
  int t0 = gw, t1 = gw + 4096;
  bool has1 = t1 < NTILE;

  const unsigned short* Ap0 = preb + (size_t)(t0 * 16 + l16) * DD + lhi * 8;
  const unsigned short* Ah0 = hb + (size_t)(t0 * 16 + l16) * DD + lhi * 8;
  s16x8 a0[8], a1[8];
#pragma unroll
  for (int ks = 0; ks < 4; ks++) a0[ks] = *(const s16x8*)(Ap0 + ks * 32);
#pragma unroll
  for (int ks = 0; ks < 4; ks++) a0[4 + ks] = *(const s16x8*)(Ah0 + ks * 32);
  if (has1) {
    const unsigned short* Ap1 = preb + (size_t)(t1 * 16 + l16) * DD + lhi * 8;
    const unsigned short* Ah1 = hb + (size_t)(t1 * 16 + l16) * DD + lhi * 8;
#pragma unroll
    for (int ks = 0; ks < 4; ks++) a1[ks] = *(const s16x8*)(Ap1 + ks * 32);
#pragma unroll
    for (int ks = 0; ks < 4; ks++) a1[4 + ks] = *(const s16x8*)(Ah1 + ks * 32);
  }

  {
    f32x4 acc[8];
#pragma unroll
    for (int n = 0; n < 8; n++) acc[n] = (f32x4){0.f, 0.f, 0.f, 0.f};
#pragma unroll
    for (int n = 0; n < 8; n++) {
#pragma unroll
      for (int k = 0; k < 8; k++) {
        s16x8 b = *(const s16x8*)(Bl + (n * 8 + k) * 512);
        acc[n] = __builtin_amdgcn_mfma_f32_16x16x32_bf16(a0[k], b, acc[n], 0, 0, 0);
      }
    }
    int r0 = t0 * 16;
#pragma unroll
    for (int n = 0; n < 8; n++) {
#pragma unroll
      for (int j = 0; j < 4; j++) {
        int gr = r0 + lhi * 4 + j;
        float x = acc[n][j];
        x = x > 0.f ? x : x * SLOPE;
        if (OUTF32) ((float*)outp)[(size_t)gr * DD + n * 16 + l16] = x;
        else ((unsigned short*)outp)[(size_t)gr * DD + n * 16 + l16] = f2b(x);
      }
    }
  }
  if (has1) {
    f32x4 acc[8];
#pragma unroll
    for (int n = 0; n < 8; n++) acc[n] = (f32x4){0.f, 0.f, 0.f, 0.f};
#pragma unroll
    for (int n = 0; n < 8; n++) {
#pragma unroll
      for (int k = 0; k < 8; k++) {
        s16x8 b = *(const s16x8*)(Bl + (n * 8 + k) * 512);
        acc[n] = __builtin_amdgcn_mfma_f32_16x16x32_bf16(a1[k], b, acc[n], 0, 0, 0);
      }
    }
    int r0 = t1 * 16;
#pragma unroll
    for (int n = 0; n < 8; n++) {
#pragma unroll
      for (int j = 0; j < 4; j++) {
        int gr = r0 + lhi * 4 + j;
        float x = acc[n][j];
        x = x > 0.f ? x : x * SLOPE;
        if (OUTF32) ((float*)outp)[(size_t)gr * DD + n * 16 + l16] = x;
        else ((unsigned short*)outp)[(size_t)gr * DD + n * 16 + l16] = f2b(x);
      }
    }
  }
}

extern "C" void kernel_launch(void* const* d_in, const int* in_sizes, int n_in,
                              void* d_out, int out_size, void* d_ws, size_t ws_size,
                              hipStream_t stream) {
  const float* ent  = (const float*)d_in[0];
  const float* rel  = (const float*)d_in[1];
  const float* norm = (const float*)d_in[2];
  const float* Wr0  = (const float*)d_in[3];
  const float* Wl0  = (const float*)d_in[4];
  const float* Wr1  = (const float*)d_in[5];
  const float* Wl1  = (const float*)d_in[6];
  const int* src = (const int*)d_in[7];
  const int* dst = (const int*)d_in[8];
  const int* rid = (const int*)d_in[9];
  float* out = (float*)d_out;

  char* ws = (char*)d_ws;
  unsigned short* entb    = (unsigned short*)ws;                  // (NN+1)*256 = 25,600,256 B
  unsigned short* preb    = (unsigned short*)(ws + 25600256);     // 25,600,000 B
  unsigned short* relaggn = (unsigned short*)(ws + 51200256);     // 25,600,000 B
  unsigned short* Wt      = (unsigned short*)(ws + 76800256);     //    131,072 B (fragment-major)
  unsigned short* relb    = (unsigned short*)(ws + 76931328);     // 501*256 = 128,256 B
  int* off   = (int*)(ws + 77059584);                             //    400,016 B
  int* bktcur = (int*)(ws + 77459600);                            //        784 B
  int* psum  = (int*)(ws + 77860384);                             //        512 B
  unsigned* epack = (unsigned*)(ws + 77860896);                   //  4,001,792 B
  // staging aliases relaggn (dead until gather1):
  unsigned* sval = (unsigned*)relaggn;                            // 196*12288*4 = 9,633,792 B
  unsigned short* sdst = (unsigned short*)(ws + 51200256 + 9633792); // 4,816,896 B

  prep_all<<<((NN + 1) * 16 + 255) / 256, 256, 0, stream>>>(ent, rel, Wr0, Wl0, Wr1, Wl1, entb, relb, Wt);

  scan_a<<<NB1, 256, 0, stream>>>(norm, psum);
  scan_b<<<1, 128, 0, stream>>>(psum, off);
  scan_c<<<NB1, 256, 0, stream>>>(norm, psum, off);

  hipMemsetAsync(bktcur, 0, NBKT * 4, stream);
  bin_scatter<<<(NE + EPB - 1) / EPB, 256, 0, stream>>>(src, dst, rid, bktcur, sval, sdst);
  bin_sort<<<NBKT, 256, 0, stream>>>(bktcur, sval, sdst, off, epack);

  const int gb = (NN * 32 + 255) / 256;

  // layer 1: gather h+rel from entb/relb; mm writes bf16 h1 in place of entb
  gather1<<<gb, 256, 0, stream>>>(entb, relb, norm, off, epack, preb, relaggn);
  layer_mm<0><<<512, 512, 0, stream>>>(preb, entb, Wt, entb);

  // layer 2: gather h only (rel part cached in relaggn); mm writes fp32 d_out
  gather2<<<gb, 256, 0, stream>>>(entb, relaggn, norm, off, epack, preb);
  layer_mm<1><<<512, 512, 0, stream>>>(preb, entb, Wt + 32768, out);
}